// Round 19
// baseline (684.435 us; speedup 1.0000x reference)
//
#include <hip/hip_runtime.h>

#define NNODES 50000
#define NEDGES 800000
#define NTILES ((NNODES + 255) / 256)   // 196
#define XFEAT (NNODES * 384)            // 19,200,000 (divisible by 2048)
#define XPREP_BLOCKS (XFEAT / (256 * 8))  // 9375
#define WPREP_TOTAL 344064
#define WPREP_BLOCKS (WPREP_TOTAL / 256)  // 1344
#define NODES_PER_SLICE (NNODES / 8)    // 6250
#define EDGES_PER_BLOCK 2048
#define EDGE_BLOCKS ((NEDGES + EDGES_PER_BLOCK - 1) / EDGES_PER_BLOCK)  // 391

typedef unsigned short ushort_t;
typedef __attribute__((ext_vector_type(8))) short short8;
typedef __attribute__((ext_vector_type(4))) float floatx4;

__device__ __forceinline__ float bf2f(unsigned short u) {
  union { unsigned int i; float f; } v; v.i = ((unsigned int)u) << 16; return v.f;
}
__device__ __forceinline__ unsigned short f2bf(float f) {
  union { float f; unsigned int i; } v; v.f = f;
  unsigned int r = v.i + 0x7fffu + ((v.i >> 16) & 1u);
  return (unsigned short)(r >> 16);
}

__device__ __forceinline__ void gload_lds16(const void* g, void* l) {
  __builtin_amdgcn_global_load_lds(
      (const __attribute__((address_space(1))) unsigned int*)g,
      (__attribute__((address_space(3))) unsigned int*)l, 16, 0, 0);
}

// counted vmcnt wait (compile-time immediate)
template <int N>
__device__ __forceinline__ void wait_vmcnt() {
  if constexpr (N == 0)      asm volatile("s_waitcnt vmcnt(0)" ::: "memory");
  else if constexpr (N == 3) asm volatile("s_waitcnt vmcnt(3)" ::: "memory");
  else if constexpr (N == 6) asm volatile("s_waitcnt vmcnt(6)" ::: "memory");
  else                       asm volatile("s_waitcnt vmcnt(0)" ::: "memory");
}

// ---------------- graph preprocessing ----------------
// hist/fill XCD-partitioned (v7, measured: both left top-5).

__global__ __launch_bounds__(256) void hist_kernel(const int* __restrict__ dst,
                                                   int* __restrict__ cnt) {
  int b = blockIdx.x;
  int lo = (b & 7) * NODES_PER_SLICE, hi = lo + NODES_PER_SLICE;
  int base = (b >> 3) * EDGES_PER_BLOCK + threadIdx.x;
#pragma unroll
  for (int q = 0; q < EDGES_PER_BLOCK / 256; ++q) {
    int i = base + q * 256;
    if (i < NEDGES) {
      int d = dst[i];
      if (d >= lo && d < hi) atomicAdd(&cnt[d], 1);
    }
  }
}

__global__ __launch_bounds__(256) void fill_kernel(const int* __restrict__ src,
                                                   const int* __restrict__ dst,
                                                   int* __restrict__ cursor,
                                                   int* __restrict__ col_idx) {
  int b = blockIdx.x;
  int lo = (b & 7) * NODES_PER_SLICE, hi = lo + NODES_PER_SLICE;
  int base = (b >> 3) * EDGES_PER_BLOCK + threadIdx.x;
#pragma unroll
  for (int q = 0; q < EDGES_PER_BLOCK / 256; ++q) {
    int i = base + q * 256;
    if (i < NEDGES) {
      int d = dst[i];
      int s = src[i];
      if (d >= lo && d < hi) {
        int p = atomicAdd(&cursor[d], 1);
        col_idx[p] = s;
      }
    }
  }
}

// ---- device-wide exclusive scan of cnt[0..NNODES) in 3 tiny kernels ----

__global__ __launch_bounds__(256) void tile_scan_kernel(
    const int* __restrict__ cnt, int* __restrict__ tile_pref, int* __restrict__ tile_sum) {
  __shared__ int s[256];
  int b = blockIdx.x, t = threadIdx.x;
  int i = b * 256 + t;
  int v = (i < NNODES) ? cnt[i] : 0;
  s[t] = v;
  __syncthreads();
#pragma unroll
  for (int off = 1; off < 256; off <<= 1) {
    int x = (t >= off) ? s[t - off] : 0;
    __syncthreads();
    s[t] += x;
    __syncthreads();
  }
  if (i < NNODES) tile_pref[i] = s[t] - v;   // exclusive within tile
  if (t == 255) tile_sum[b] = s[255];
}

__global__ __launch_bounds__(256) void sum_scan_kernel(
    const int* __restrict__ tile_sum, int* __restrict__ tile_base) {
  __shared__ int s[256];
  int t = threadIdx.x;
  int v = (t < NTILES) ? tile_sum[t] : 0;
  s[t] = v;
  __syncthreads();
#pragma unroll
  for (int off = 1; off < 256; off <<= 1) {
    int x = (t >= off) ? s[t - off] : 0;
    __syncthreads();
    s[t] += x;
    __syncthreads();
  }
  if (t < NTILES) tile_base[t] = s[t] - v;   // exclusive across tiles
}

__global__ __launch_bounds__(256) void scan_write_kernel(
    const int* __restrict__ cnt, const int* __restrict__ tile_pref,
    const int* __restrict__ tile_base, int* __restrict__ row_ptr,
    int* __restrict__ cursor, float* __restrict__ dinv) {
  int b = blockIdx.x, t = threadIdx.x;
  int i = b * 256 + t;
  if (i < NNODES) {
    int base = tile_base[b] + tile_pref[i];
    row_ptr[i] = base;
    cursor[i] = base;
    dinv[i] = rsqrtf((float)(cnt[i] + 1));  // +1 self loop
    if (i == NNODES - 1) row_ptr[NNODES] = base + cnt[i];
  }
}

// ------- merged prep: x f32->bf16 + all 5 weight transpose/hi-lo splits ----
__global__ __launch_bounds__(256) void prep_all(
    const float* __restrict__ x, ushort_t* __restrict__ xbf,
    const float* __restrict__ W1, ushort_t* __restrict__ W1h, ushort_t* __restrict__ W1l,
    const float* __restrict__ W2, ushort_t* __restrict__ W2h, ushort_t* __restrict__ W2l,
    const float* __restrict__ W3, ushort_t* __restrict__ W3h, ushort_t* __restrict__ W3l,
    const float* __restrict__ W4, ushort_t* __restrict__ W4h, ushort_t* __restrict__ W4l,
    const float* __restrict__ Wl, ushort_t* __restrict__ Wlh, ushort_t* __restrict__ Wll) {
  int b = blockIdx.x;
  if (b < XPREP_BLOCKS) {
    size_t i = ((size_t)b * 256 + threadIdx.x) * 8;
    float4 p0 = *(const float4*)(x + i);
    float4 p1 = *(const float4*)(x + i + 4);
    uint4 u;
    u.x = (unsigned int)f2bf(p0.x) | ((unsigned int)f2bf(p0.y) << 16);
    u.y = (unsigned int)f2bf(p0.z) | ((unsigned int)f2bf(p0.w) << 16);
    u.z = (unsigned int)f2bf(p1.x) | ((unsigned int)f2bf(p1.y) << 16);
    u.w = (unsigned int)f2bf(p1.z) | ((unsigned int)f2bf(p1.w) << 16);
    *(uint4*)(xbf + i) = u;
    return;
  }
  int t = (b - XPREP_BLOCKS) * 256 + threadIdx.x;
  const float* W; ushort_t* hi; ushort_t* lo; int K, N;
  if (t < 49152)       { W = W1; hi = W1h; lo = W1l; K = 384; N = 128; }
  else if (t < 98304)  { W = W2; hi = W2h; lo = W2l; K = 128; N = 384; t -= 49152; }
  else if (t < 196608) { W = W3; hi = W3h; lo = W3l; K = 384; N = 256; t -= 98304; }
  else if (t < 294912) { W = W4; hi = W4h; lo = W4l; K = 256; N = 384; t -= 196608; }
  else                 { W = Wl; hi = Wlh; lo = Wll; K = 384; N = 128; t -= 294912; }
  int n = t / K, k = t - n * K;
  float w = W[(size_t)k * N + n];
  unsigned short h = f2bf(w);
  hi[t] = h;
  lo[t] = f2bf(w - bf2f(h));
}

// ---------------- aggregation v2b: 64B line-slices, L2-resident per XCD ----
// Mapping (kept from v9): row cut into 64B line-slices; one slice per XCD
// role (C=256: 8 slices; C=128: 4 slices x 2 node-halves). Per-XCD gather
// working set = 50000x64B = 3.2MB < 4MB L2. 16 lanes per node (uint = 2ch),
// 4 node-groups per wave.
// Machinery (REVERTED to the measured-passing structure after v9's absmax
// failure): exact trip counts -- early-exit guard, 4-wide unrolled loop +
// scalar remainder, every col_idx index strictly in [e,e1). No shfl/clamp/
// predication. Group-divergent trip counts handled by exec mask.
// Inputs PRE-SCALED by source dinv. mode 0: plain; 1: +bias leaky(0.01).

template <int C>  // 128 or 256
__global__ __launch_bounds__(256) void agg_kernel(
    const ushort_t* __restrict__ in, ushort_t* __restrict__ out,
    const int* __restrict__ row_ptr, const int* __restrict__ col_idx,
    const float* __restrict__ dinv, const float* __restrict__ bias,
    int mode, int scale_store) {
  constexpr int NSL = (C * 2) / 64;     // line-slices per row: 256->8, 128->4
  int b = blockIdx.x;
  int role = b & 7;                     // de-facto XCD under round-robin
  int slice = role & (NSL - 1);
  int nbase = (NSL == 8) ? 0 : (role >> 2) * (NNODES / 2);
  int nn = (NSL == 8) ? NNODES : (NNODES / 2);
  int idx = b >> 3;
  int lane = threadIdx.x & 63;
  int wv = threadIdx.x >> 6;
  int g = lane >> 4, sub = lane & 15;
  int node = nbase + idx * 16 + wv * 4 + g;
  if (node >= nbase + nn) return;       // tail guard (group-uniform exit)
  int co = slice * 32 + sub * 2;        // channel offset, 2 ch per lane
  const ushort_t* basep = in + co;
  int e = row_ptr[node], e1 = row_ptr[node + 1];
  float acc0, acc1;
  {
    unsigned int u = *(const unsigned int*)(basep + (size_t)node * C);
    acc0 = bf2f((unsigned short)(u & 0xffff));
    acc1 = bf2f((unsigned short)(u >> 16));
  }
  for (; e + 4 <= e1; e += 4) {
    int j0 = col_idx[e], j1 = col_idx[e + 1], j2 = col_idx[e + 2], j3 = col_idx[e + 3];
    unsigned int u0 = *(const unsigned int*)(basep + (size_t)j0 * C);
    unsigned int u1 = *(const unsigned int*)(basep + (size_t)j1 * C);
    unsigned int u2 = *(const unsigned int*)(basep + (size_t)j2 * C);
    unsigned int u3 = *(const unsigned int*)(basep + (size_t)j3 * C);
    acc0 += (bf2f((unsigned short)(u0 & 0xffff)) + bf2f((unsigned short)(u1 & 0xffff))) +
            (bf2f((unsigned short)(u2 & 0xffff)) + bf2f((unsigned short)(u3 & 0xffff)));
    acc1 += (bf2f((unsigned short)(u0 >> 16)) + bf2f((unsigned short)(u1 >> 16))) +
            (bf2f((unsigned short)(u2 >> 16)) + bf2f((unsigned short)(u3 >> 16)));
  }
  for (; e < e1; ++e) {
    int j = col_idx[e];
    unsigned int u = *(const unsigned int*)(basep + (size_t)j * C);
    acc0 += bf2f((unsigned short)(u & 0xffff));
    acc1 += bf2f((unsigned short)(u >> 16));
  }
  float di = dinv[node];
  if (mode) {
    float2 b2 = *(const float2*)(bias + co);
    float sc = scale_store ? di : 1.f;
    float x0 = acc0 * di + b2.x; x0 = x0 > 0.f ? x0 : 0.01f * x0;
    float x1 = acc1 * di + b2.y; x1 = x1 > 0.f ? x1 : 0.01f * x1;
    acc0 = x0 * sc; acc1 = x1 * sc;
  } else {
    acc0 *= di; acc1 *= di;
  }
  *(unsigned int*)(out + (size_t)node * C + co) =
      (unsigned int)f2bf(acc0) | ((unsigned int)f2bf(acc1) << 16);
}

// ---------------- MFMA GEMM: C = A[M,K] @ (Bhi+Blo)[N,K]^T ----------------
// v8 counted-vmcnt pipeline (measured r11: all gemms left top-5).
// mode 0: raw; 1: +bias leaky; 2: +bias relu. scale_store: *dinv[row].

#define BK 32

template <int TB>
__device__ __forceinline__ void stage_tile(const ushort_t* __restrict__ G, int g0,
                                           int K, int kb, ushort_t* lds,
                                           int tid, int w, int Mclamp) {
  constexpr int IT = TB / 64;
#pragma unroll
  for (int it = 0; it < IT; ++it) {
    int s = it * 256 + tid;
    int row = s >> 2;                      // row within tile (4 lanes per row)
    int j = (s & 3) ^ ((s >> 3) & 3);      // source k-chunk for dest slot s&3
    int gr = g0 + row; if (gr > Mclamp - 1) gr = Mclamp - 1;
    gload_lds16(G + (size_t)gr * K + kb + j * 8,
                lds + (size_t)(it * 256 + w * 64) * 8);
  }
}

template <int TBM, int TBN>
__global__ __launch_bounds__(256, TBM == 64 ? 6 : 3) void gemm_mfma(
    const ushort_t* __restrict__ A, const ushort_t* __restrict__ Bhi,
    const ushort_t* __restrict__ Blo, void* __restrict__ Cv,
    const float* __restrict__ bias, const float* __restrict__ dinv,
    int M, int K, int ldc, int mode, int scale_store, int out_f32) {
  constexpr int FR = TBM / 32;        // A fragments per wave
  constexpr int FG = TBN / 32;        // B fragments per wave
  constexpr int NLD = TBM / 64 + 2 * (TBN / 64);  // staging instrs/wave/K-step
  __shared__ ushort_t As[2][TBM * BK];
  __shared__ ushort_t Bh[2][TBN * BK];
  __shared__ ushort_t Bl[2][TBN * BK];
  int tid = threadIdx.x;
  int lane = tid & 63, w = tid >> 6;
  int wm = w & 1, wn = w >> 1;

  // bijective XCD chunk remap, tx-major tile order
  int lin = blockIdx.y * gridDim.x + blockIdx.x;
  int nwg = gridDim.x * gridDim.y;
  int q = nwg >> 3, r = nwg & 7, xc = lin & 7, sdx = lin >> 3;
  int wg = (xc < r ? xc * (q + 1) : r * (q + 1) + (xc - r) * q) + sdx;
  int nty = gridDim.y;
  int tx = wg / nty, ty = wg - tx * nty;
  int m0 = tx * TBM, n0 = ty * TBN;

  floatx4 acc[FR][FG] = {};
  int nkt = K / BK;
  int cur = 0;
  // prologue: stage K-step 0 (no drain; iteration 0's counted wait covers it)
  stage_tile<TBM>(A, m0, K, 0, As[0], tid, w, M);
  stage_tile<TBN>(Bhi, n0, K, 0, Bh[0], tid, w, 1 << 30);
  stage_tile<TBN>(Blo, n0, K, 0, Bl[0], tid, w, 1 << 30);
  int rr = lane & 15, jj = lane >> 4;
  for (int kt = 0; kt < nkt; ++kt) {
    if (kt + 1 < nkt) {
      int kb = (kt + 1) * BK;
      stage_tile<TBM>(A, m0, K, kb, As[cur ^ 1], tid, w, M);
      stage_tile<TBN>(Bhi, n0, K, kb, Bh[cur ^ 1], tid, w, 1 << 30);
      stage_tile<TBN>(Blo, n0, K, kb, Bl[cur ^ 1], tid, w, 1 << 30);
      wait_vmcnt<NLD>();   // my tile-t loads landed; t+1 batch stays in flight
    } else {
      wait_vmcnt<0>();     // final tile: drain
    }
    __builtin_amdgcn_s_barrier();        // all waves' tile-t loads landed
    __builtin_amdgcn_sched_barrier(0);   // pin: no reads hoisted above
    short8 af[FR], fh[FG], fl[FG];
#pragma unroll
    for (int f = 0; f < FR; ++f) {
      int fr_row = wm * (TBM / 2) + f * 16 + rr;
      af[f] = *(const short8*)&As[cur][fr_row * BK + ((jj ^ ((fr_row >> 1) & 3)) * 8)];
    }
#pragma unroll
    for (int g = 0; g < FG; ++g) {
      int fb_row = wn * (TBN / 2) + g * 16 + rr;
      int o = fb_row * BK + ((jj ^ ((fb_row >> 1) & 3)) * 8);
      fh[g] = *(const short8*)&Bh[cur][o];
      fl[g] = *(const short8*)&Bl[cur][o];
    }
#pragma unroll
    for (int f = 0; f < FR; ++f)
#pragma unroll
      for (int g = 0; g < FG; ++g) {
        acc[f][g] = __builtin_amdgcn_mfma_f32_16x16x32_bf16(af[f], fh[g], acc[f][g], 0, 0, 0);
        acc[f][g] = __builtin_amdgcn_mfma_f32_16x16x32_bf16(af[f], fl[g], acc[f][g], 0, 0, 0);
      }
    __builtin_amdgcn_sched_barrier(0);   // pin: reads/MFMA stay above barrier
    __builtin_amdgcn_s_barrier();        // all reads of buf[cur] done -> restage safe
    cur ^= 1;
  }
  int cr = lane >> 4, cc = lane & 15;
#pragma unroll
  for (int f = 0; f < FR; ++f) {
#pragma unroll
    for (int r2 = 0; r2 < 4; ++r2) {
      int row = m0 + wm * (TBM / 2) + f * 16 + cr * 4 + r2;
      if (row >= M) continue;
      float sc = scale_store ? dinv[row] : 1.f;
#pragma unroll
      for (int g = 0; g < FG; ++g) {
        int col = n0 + wn * (TBN / 2) + g * 16 + cc;
        float v = acc[f][g][r2];
        if (mode) {
          v += bias[col];
          v = (mode == 1) ? (v > 0.f ? v : 0.01f * v) : (v > 0.f ? v : 0.f);
        }
        v *= sc;
        if (out_f32) ((float*)Cv)[(size_t)row * ldc + col] = v;
        else ((ushort_t*)Cv)[(size_t)row * ldc + col] = f2bf(v);
      }
    }
  }
}

// ---------------- driver ----------------

extern "C" void kernel_launch(void* const* d_in, const int* in_sizes, int n_in,
                              void* d_out, int out_size, void* d_ws, size_t ws_size,
                              hipStream_t stream) {
  const float* x  = (const float*)d_in[0];
  const int* ei   = (const int*)d_in[1];
  const float* W1 = (const float*)d_in[2];
  const float* b1 = (const float*)d_in[3];
  const float* W2 = (const float*)d_in[4];
  const float* b2 = (const float*)d_in[5];
  const float* W3 = (const float*)d_in[6];
  const float* b3 = (const float*)d_in[7];
  const float* W4 = (const float*)d_in[8];
  const float* b4 = (const float*)d_in[9];
  const float* Wl = (const float*)d_in[10];
  const float* bl = (const float*)d_in[11];

  char* p = (char*)d_ws;
  auto alloc = [&](size_t bytes) {
    char* r = p;
    p += (bytes + 255) & ~(size_t)255;
    return r;
  };
  int* cnt       = (int*)alloc((size_t)NNODES * 4);
  int* cursor    = (int*)alloc((size_t)NNODES * 4);
  int* row_ptr   = (int*)alloc((size_t)(NNODES + 1) * 4);
  float* dinv    = (float*)alloc((size_t)NNODES * 4);
  int* col_idx   = (int*)alloc((size_t)NEDGES * 4);
  int* tile_pref = (int*)alloc((size_t)NNODES * 4);
  int* tile_sum  = (int*)alloc(256 * 4);
  int* tile_base = (int*)alloc(256 * 4);
  ushort_t* W1h = (ushort_t*)alloc(49152 * 2); ushort_t* W1l = (ushort_t*)alloc(49152 * 2);
  ushort_t* W2h = (ushort_t*)alloc(49152 * 2); ushort_t* W2l = (ushort_t*)alloc(49152 * 2);
  ushort_t* W3h = (ushort_t*)alloc(98304 * 2); ushort_t* W3l = (ushort_t*)alloc(98304 * 2);
  ushort_t* W4h = (ushort_t*)alloc(98304 * 2); ushort_t* W4l = (ushort_t*)alloc(98304 * 2);
  ushort_t* Wlh = (ushort_t*)alloc(49152 * 2); ushort_t* Wll = (ushort_t*)alloc(49152 * 2);
  ushort_t* actA = (ushort_t*)alloc((size_t)NNODES * 384 * 2);
  ushort_t* actB = (ushort_t*)alloc((size_t)NNODES * 384 * 2);
  // xbf aliases actB: actB is first written by L1-agg, by which time the
  // bf16 copy of x (read only by the L1 gemm) is dead.
  ushort_t* xbf = actB;

  const int* src = ei;
  const int* dst = ei + NEDGES;

  hipMemsetAsync(cnt, 0, (size_t)NNODES * 4, stream);
  hist_kernel<<<EDGE_BLOCKS * 8, 256, 0, stream>>>(dst, cnt);
  tile_scan_kernel<<<NTILES, 256, 0, stream>>>(cnt, tile_pref, tile_sum);
  sum_scan_kernel<<<1, 256, 0, stream>>>(tile_sum, tile_base);
  scan_write_kernel<<<NTILES, 256, 0, stream>>>(cnt, tile_pref, tile_base, row_ptr, cursor, dinv);
  fill_kernel<<<EDGE_BLOCKS * 8, 256, 0, stream>>>(src, dst, cursor, col_idx);

  prep_all<<<XPREP_BLOCKS + WPREP_BLOCKS, 256, 0, stream>>>(
      x, xbf, W1, W1h, W1l, W2, W2h, W2l, W3, W3h, W3l, W4, W4h, W4l, Wl, Wlh, Wll);

  dim3 blk(256);
  int gm64  = (NNODES + 63) / 64;    // 782
  int gm128 = (NNODES + 127) / 128;  // 391
  int gagg128 = 8 * 1563;            // 4 slices x 2 node-halves, 16 nodes/block
  int gagg256 = 8 * 3125;            // 8 slices, 16 nodes/block (50000/16 exact)

  // L1 (384->128): gemm reads xbf (pre-scaled store), agg(+b1, leaky, pre-scaled)
  gemm_mfma<64, 64><<<dim3(gm64, 2), blk, 0, stream>>>(xbf, W1h, W1l, actA, (const float*)0, dinv, NNODES, 384, 128, 0, 1, 0);
  agg_kernel<128><<<gagg128, blk, 0, stream>>>(actA, actB, row_ptr, col_idx, dinv, b1, 1, 1);
  // L2 (128->384): agg (plain), gemm(+b2, leaky)
  agg_kernel<128><<<gagg128, blk, 0, stream>>>(actB, actA, row_ptr, col_idx, dinv, (const float*)0, 0, 0);
  gemm_mfma<128, 128><<<dim3(gm128, 3), blk, 0, stream>>>(actA, W2h, W2l, actB, b2, dinv, NNODES, 128, 384, 1, 0, 0);
  // L3 (384->256): gemm (pre-scaled store), agg(+b3, leaky, pre-scaled store)
  gemm_mfma<128, 128><<<dim3(gm128, 2), blk, 0, stream>>>(actB, W3h, W3l, actA, (const float*)0, dinv, NNODES, 384, 256, 0, 1, 0);
  agg_kernel<256><<<gagg256, blk, 0, stream>>>(actA, actB, row_ptr, col_idx, dinv, b3, 1, 1);
  // L4 (256->384): agg (plain), gemm(+b4, leaky)
  agg_kernel<256><<<gagg256, blk, 0, stream>>>(actB, actA, row_ptr, col_idx, dinv, (const float*)0, 0, 0);
  gemm_mfma<128, 128><<<dim3(gm128, 3), blk, 0, stream>>>(actA, W4h, W4l, actB, b4, dinv, NNODES, 256, 384, 1, 0, 0);
  // final linear (384->128) + relu -> d_out (f32)
  gemm_mfma<64, 64><<<dim3(gm64, 2), blk, 0, stream>>>(actB, Wlh, Wll, d_out, bl, dinv, NNODES, 384, 128, 2, 0, 1);
}